// Round 1
// baseline (209.770 us; speedup 1.0000x reference)
//
#include <hip/hip_runtime.h>

// Causal GQA attention prefill, fp32 in/out, MFMA 32x32x16 bf16 compute.
// S=2048, H=32, KVH=8 (rep=4), D=128.
// Round 6 on top of round 5:
//   1) LDS double-buffer for K/V + raw lgkm-only barrier (1/tile instead of
//      2 full-drain __syncthreads) -> global prefetch stays in flight across
//      barriers (T3/T4 counted-vmcnt analog).
//   2) In-register P repack (T12): v_cvt_pk_bf16_f32 + permlane32_swap
//      replaces the ps[] LDS buffer (16 4-way-conflicted writes + 4 reads +
//      ~80 VALU of software f2bf per tile). ps removed entirely.
//   3) Defer-max (T13, THR=8 in log2 domain): O-rescale skipped when wave
//      max is stable; SCALE*log2e folded into Q conversion; exp via exp2f
//      (single v_exp_f32); tree-shaped max/sum; lane^32 exchange via
//      permlane32_swap (VALU) instead of LDS shuffle; s_setprio around MFMA.

#define SEQ   2048
#define NH    32
#define NKVH  8
#define HD    128
#define BQ    128
#define BK    64
#define KSS   136   // ks stride (ushort)
#define VTS   72    // vt stride (ushort)
#define PSS   72    // ps stride (ushort) - fallback kernel only
#define SCALE 0.08838834764831845f
#define QS    (0.08838834764831845f * 1.4426950408889634f)   // SCALE * log2(e)

#define KB_ELEMS (SEQ * NKVH * HD)          // 2,097,152 ushorts
#define WS_NEED  (2u * KB_ELEMS * 2u)       // kb + vtw, bytes

typedef __attribute__((ext_vector_type(8)))  short short8;
typedef __attribute__((ext_vector_type(16))) float float16;
typedef __attribute__((ext_vector_type(2)))  unsigned int uint2v;

__device__ __forceinline__ unsigned short f2bf(float f) {
    union { float f; unsigned int i; } x; x.f = f;
    unsigned int r = x.i + 0x7fffu + ((x.i >> 16) & 1u);   // RNE
    return (unsigned short)(r >> 16);
}
__device__ __forceinline__ unsigned int f2bf2(float lo, float hi) {
    return (unsigned int)f2bf(lo) | ((unsigned int)f2bf(hi) << 16);
}
__device__ __forceinline__ unsigned int cvt_pk_bf16(float lo, float hi) {
    unsigned int r;
    asm("v_cvt_pk_bf16_f32 %0, %1, %2" : "=v"(r) : "v"(lo), "v"(hi));
    return r;
}

// permlane32_swap: newD[l>=32] = S_old[l-32]; newS[l<32] = D_old[l+32];
// other halves unchanged.  (vdst, src) -> (xout, yout)
#if __has_builtin(__builtin_amdgcn_permlane32_swap)
#define PLSWAP(a, b, xout, yout) do { \
    uint2v r_ = __builtin_amdgcn_permlane32_swap((a), (b), false, false); \
    (xout) = r_.x; (yout) = r_.y; } while (0)
#else
#define PLSWAP(a, b, xout, yout) do { \
    unsigned int a_ = (a), b_ = (b); \
    asm volatile("s_nop 1\n\tv_permlane32_swap_b32 %0, %1" : "+v"(a_), "+v"(b_)); \
    (xout) = a_; (yout) = b_; } while (0)
#endif

// Build one PV A-fragment (8 bf16: keys kcbase*16 + half*8 + 0..7) from the
// 8 fp32 P values sv[b..b+7] held per-lane in the S^T layout.
#define MAKE_AF(dst, sv, b) do { \
    const unsigned int p0_ = cvt_pk_bf16(sv[(b) + 0], sv[(b) + 1]); \
    const unsigned int p1_ = cvt_pk_bf16(sv[(b) + 2], sv[(b) + 3]); \
    const unsigned int p2_ = cvt_pk_bf16(sv[(b) + 4], sv[(b) + 5]); \
    const unsigned int p3_ = cvt_pk_bf16(sv[(b) + 6], sv[(b) + 7]); \
    unsigned int w0_, w1_, w2_, w3_; \
    PLSWAP(p0_, p2_, w0_, w2_); \
    PLSWAP(p1_, p3_, w1_, w3_); \
    union { short8 v; unsigned int u[4]; } uu_; \
    uu_.u[0] = w0_; uu_.u[1] = w1_; uu_.u[2] = w2_; uu_.u[3] = w3_; \
    (dst) = uu_.v; } while (0)

// ---- prep: K fp32 -> bf16, natural [s][kvh][d] ----
__global__ __launch_bounds__(256)
void cvt_k(const float* __restrict__ k, unsigned short* __restrict__ kb)
{
    const int i = (blockIdx.x * 256 + threadIdx.x) * 4;
    const float4 a = *(const float4*)(k + i);
    uint2 o; o.x = f2bf2(a.x, a.y); o.y = f2bf2(a.z, a.w);
    *(uint2*)(kb + i) = o;
}

// ---- prep: V fp32 -> bf16 transposed tiles vtw[kvh][jt][d][key64] ----
__global__ __launch_bounds__(256)
void cvt_v(const float* __restrict__ v, unsigned short* __restrict__ vtw)
{
    __shared__ unsigned short tl[HD * VTS];
    const int t   = threadIdx.x;
    const int jt  = blockIdx.x & 31;
    const int kvh = blockIdx.x >> 5;
    const int dp  = (t & 63) * 2;
    const int k0  = t >> 6;
    #pragma unroll
    for (int r = 0; r < 16; ++r) {
        const int key = k0 + r * 4;
        const float2 a =
            *(const float2*)(v + ((size_t)(jt * 64 + key) * NKVH + kvh) * HD + dp);
        tl[dp * VTS + key]       = f2bf(a.x);
        tl[(dp + 1) * VTS + key] = f2bf(a.y);
    }
    __syncthreads();
    unsigned short* dst = vtw + (size_t)(kvh * 32 + jt) * HD * 64;
    const int c  = t & 7;
    const int d0 = t >> 3;
    #pragma unroll
    for (int r = 0; r < 4; ++r) {
        const int d = d0 + r * 32;
        *(uint4*)(dst + d * 64 + c * 8) = *(const uint4*)&tl[d * VTS + c * 8];
    }
}

// ---- main ----
__global__ __launch_bounds__(256, 2)
void attn_fwd2(const float* __restrict__ q,
               const unsigned short* __restrict__ kb,
               const unsigned short* __restrict__ vtw,
               float* __restrict__ out)
{
    __shared__ unsigned short ks[2][BK * KSS];
    __shared__ unsigned short vt[2][HD * VTS];
    __shared__ float          alf[4][32];

    const int t    = threadIdx.x;
    const int w    = t >> 6;
    const int lane = t & 63;
    const int ln   = lane & 31;
    const int half = lane >> 5;

    // work-complementary pairing: blocks i and i+256 -> q-tiles px, 15-px
    const int pair = blockIdx.x & 255;
    const int late = blockIdx.x >> 8;
    const int h    = pair & 31;
    const int px   = pair >> 5;                 // 0..7
    const int bx   = late ? (15 - px) : px;
    const int kvh  = h >> 2;                    // repeat_interleave rep=4
    const int q0   = bx * BQ;
    const int wq0  = q0 + w * 32;
    const int qrow = wq0 + ln;
    const int ntiles = q0 / BK + 2;
    const int wqmax  = wq0 + 31;

    // staging decompositions
    const int skey = t >> 2, sc = t & 3;        // K: 4 thr/key, 16B chunks
    const int vc = t & 7, vd0 = t >> 3;         // V: linear copy rows
    const unsigned short* vtile0 = vtw + (size_t)(kvh * 32) * HD * 64;

    // ---- Q fragments, pre-scaled by SCALE*log2(e) ----
    short8 qf[8];
    {
        const float* qr = q + ((size_t)qrow * NH + h) * HD;
        #pragma unroll
        for (int k0 = 0; k0 < 8; ++k0) {
            const float* p4 = qr + k0 * 16 + half * 8;
            const float4 a = *(const float4*)(p4);
            const float4 b = *(const float4*)(p4 + 4);
            union { short8 v; unsigned int u[4]; } uu;
            uu.u[0] = f2bf2(a.x * QS, a.y * QS);
            uu.u[1] = f2bf2(a.z * QS, a.w * QS);
            uu.u[2] = f2bf2(b.x * QS, b.y * QS);
            uu.u[3] = f2bf2(b.z * QS, b.w * QS);
            qf[k0] = uu.v;
        }
    }

    float16 o0, o1, o2, o3;
    #pragma unroll
    for (int i = 0; i < 16; ++i) { o0[i] = 0.f; o1[i] = 0.f; o2[i] = 0.f; o3[i] = 0.f; }
    float m_run = -1e30f, l_run = 0.f;

    uint4 kpre[4], vpre[4];

#define PREFETCH(tidx) do { \
    const unsigned short* krow_ = \
        kb + ((size_t)((tidx) * BK + skey) * NKVH + kvh) * HD + sc * 8; \
    kpre[0] = *(const uint4*)(krow_);       kpre[1] = *(const uint4*)(krow_ + 32); \
    kpre[2] = *(const uint4*)(krow_ + 64);  kpre[3] = *(const uint4*)(krow_ + 96); \
    const unsigned short* vrow_ = vtile0 + (size_t)(tidx) * (HD * 64) + (size_t)t * 8; \
    vpre[0] = *(const uint4*)(vrow_);        vpre[1] = *(const uint4*)(vrow_ + 2048); \
    vpre[2] = *(const uint4*)(vrow_ + 4096); vpre[3] = *(const uint4*)(vrow_ + 6144); \
} while (0)

#define STAGE(bufi) do { \
    unsigned short* kdst_ = &ks[bufi][skey * KSS + sc * 8]; \
    *(uint4*)(kdst_)      = kpre[0]; *(uint4*)(kdst_ + 32) = kpre[1]; \
    *(uint4*)(kdst_ + 64) = kpre[2]; *(uint4*)(kdst_ + 96) = kpre[3]; \
    unsigned short* vdst_ = &vt[bufi][vd0 * VTS + vc * 8]; \
    *(uint4*)(vdst_)            = vpre[0]; *(uint4*)(vdst_ + 32 * VTS) = vpre[1]; \
    *(uint4*)(vdst_ + 64 * VTS) = vpre[2]; *(uint4*)(vdst_ + 96 * VTS) = vpre[3]; \
} while (0)

// lgkm-only barrier: LDS producer/consumer ordering WITHOUT draining vmcnt,
// so register prefetch loads stay in flight across the barrier.
#define BARRIER() do { \
    asm volatile("s_waitcnt lgkmcnt(0)" ::: "memory"); \
    __builtin_amdgcn_s_barrier(); \
    asm volatile("" ::: "memory"); \
} while (0)

    PREFETCH(0);
    STAGE(0);
    if (ntiles > 1) PREFETCH(1);
    BARRIER();

    for (int it = 0; it < ntiles; ++it) {
        const int cur = it & 1;
        const int j0  = it * BK;

        // write prefetched tile it+1 to the other buffer; issue tile it+2
        if (it + 1 < ntiles) STAGE(1 - cur);
        if (it + 2 < ntiles) PREFETCH(it + 2);

        if (j0 <= wqmax) {
            const unsigned short* ksb = ks[cur];
            const unsigned short* vtb = vt[cur];

            // ---- S^T = K Q^T (pre-scaled, log2 domain) ----
            float16 st0, st1;
            #pragma unroll
            for (int i = 0; i < 16; ++i) { st0[i] = 0.f; st1[i] = 0.f; }
            __builtin_amdgcn_s_setprio(1);
            #pragma unroll
            for (int k0 = 0; k0 < 8; ++k0) {
                const short8 a0 = *(const short8*)&ksb[ln * KSS + k0 * 16 + half * 8];
                const short8 a1 = *(const short8*)&ksb[(32 + ln) * KSS + k0 * 16 + half * 8];
                st0 = __builtin_amdgcn_mfma_f32_32x32x16_bf16(a0, qf[k0], st0, 0, 0, 0);
                st1 = __builtin_amdgcn_mfma_f32_32x32x16_bf16(a1, qf[k0], st1, 0, 0, 0);
            }
            __builtin_amdgcn_s_setprio(0);

            // ---- causal mask (diagonal tiles only) ----
            if ((j0 + BK - 1) > wq0) {
                #pragma unroll
                for (int r = 0; r < 16; ++r) {
                    const int kl = (r & 3) + 8 * (r >> 2) + 4 * half;
                    if (j0 + kl > qrow)      st0[r] = -1e30f;
                    if (j0 + 32 + kl > qrow) st1[r] = -1e30f;
                }
            }

            // ---- tree max over 32 values + lane^32 exchange ----
            float m0 = fmaxf(st0[0], st1[0]), m1 = fmaxf(st0[1], st1[1]);
            float m2 = fmaxf(st0[2], st1[2]), m3 = fmaxf(st0[3], st1[3]);
            #pragma unroll
            for (int r = 4; r < 16; r += 4) {
                m0 = fmaxf(m0, fmaxf(st0[r],     st1[r]));
                m1 = fmaxf(m1, fmaxf(st0[r + 1], st1[r + 1]));
                m2 = fmaxf(m2, fmaxf(st0[r + 2], st1[r + 2]));
                m3 = fmaxf(m3, fmaxf(st0[r + 3], st1[r + 3]));
            }
            float mt = fmaxf(fmaxf(m0, m1), fmaxf(m2, m3));
            {
                unsigned int sx, sy;
                PLSWAP(__float_as_uint(mt), __float_as_uint(mt), sx, sy);
                mt = fmaxf(mt, __uint_as_float(half ? sx : sy));
            }

            // ---- defer-max: rescale only when wave max grew > 8 (log2) ----
            const bool resc = !__all(mt <= m_run + 8.f);
            const float mn  = resc ? fmaxf(m_run, mt) : m_run;

            float s0 = 0.f, s1 = 0.f, s2 = 0.f, s3 = 0.f;
            #pragma unroll
            for (int r = 0; r < 16; r += 2) {
                const float e0 = exp2f(st0[r]     - mn);
                const float e1 = exp2f(st1[r]     - mn);
                const float e2 = exp2f(st0[r + 1] - mn);
                const float e3 = exp2f(st1[r + 1] - mn);
                st0[r] = e0; st1[r] = e1; st0[r + 1] = e2; st1[r + 1] = e3;
                s0 += e0; s1 += e1; s2 += e2; s3 += e3;
            }
            float sm = (s0 + s1) + (s2 + s3);
            {
                unsigned int sx, sy;
                PLSWAP(__float_as_uint(sm), __float_as_uint(sm), sx, sy);
                sm += __uint_as_float(half ? sx : sy);
            }

            if (resc) {
                const float alpha = exp2f(m_run - mn);
                m_run = mn;
                l_run = l_run * alpha + sm;
                if (half == 0) alf[w][ln] = alpha;
                #pragma unroll
                for (int r = 0; r < 16; ++r) {
                    const int rl = (r & 3) + 8 * (r >> 2) + 4 * half;
                    const float ar = alf[w][rl];
                    o0[r] *= ar; o1[r] *= ar; o2[r] *= ar; o3[r] *= ar;
                }
            } else {
                l_run += sm;
            }

            // ---- P -> bf16 A-fragments fully in-register (T12) ----
            short8 af0, af1, af2, af3;
            MAKE_AF(af0, st0, 0);
            MAKE_AF(af1, st0, 8);
            MAKE_AF(af2, st1, 0);
            MAKE_AF(af3, st1, 8);

            // ---- PV ----
            __builtin_amdgcn_s_setprio(1);
#define PV_STEP(afx, kc) do { \
    const short8 bv0 = *(const short8*)&vtb[(ln)      * VTS + (kc) * 16 + half * 8]; \
    const short8 bv1 = *(const short8*)&vtb[(32 + ln) * VTS + (kc) * 16 + half * 8]; \
    const short8 bv2 = *(const short8*)&vtb[(64 + ln) * VTS + (kc) * 16 + half * 8]; \
    const short8 bv3 = *(const short8*)&vtb[(96 + ln) * VTS + (kc) * 16 + half * 8]; \
    o0 = __builtin_amdgcn_mfma_f32_32x32x16_bf16(afx, bv0, o0, 0, 0, 0); \
    o1 = __builtin_amdgcn_mfma_f32_32x32x16_bf16(afx, bv1, o1, 0, 0, 0); \
    o2 = __builtin_amdgcn_mfma_f32_32x32x16_bf16(afx, bv2, o2, 0, 0, 0); \
    o3 = __builtin_amdgcn_mfma_f32_32x32x16_bf16(afx, bv3, o3, 0, 0, 0); \
} while (0)
            PV_STEP(af0, 0);
            PV_STEP(af1, 1);
            PV_STEP(af2, 2);
            PV_STEP(af3, 3);
#undef PV_STEP
            __builtin_amdgcn_s_setprio(0);
        }
        BARRIER();
    }

    // ---- epilogue ----
    if (half == 0) alf[w][ln] = l_run;
    __builtin_amdgcn_s_waitcnt(0);
    #pragma unroll
    for (int r = 0; r < 16; ++r) {
        const int rl = (r & 3) + 8 * (r >> 2) + 4 * half;
        const float inv = 1.f / alf[w][rl];
        float* orow = out + ((size_t)(wq0 + rl) * NH + h) * HD;
        orow[ln]      = o0[r] * inv;
        orow[32 + ln] = o1[r] * inv;
        orow[64 + ln] = o2[r] * inv;
        orow[96 + ln] = o3[r] * inv;
    }
#undef PREFETCH
#undef STAGE
#undef BARRIER
}

// ---- fallback (round-4 kernel, no workspace needed) ----
__global__ __launch_bounds__(256, 2)
void attn_fwd_fb(const float* __restrict__ q,
                 const float* __restrict__ k,
                 const float* __restrict__ v,
                 float* __restrict__ out)
{
    __shared__ unsigned short ks[BK * KSS];
    __shared__ unsigned short vt[HD * VTS];
    __shared__ unsigned short ps[4][32 * PSS];
    __shared__ float          alf[4][32];

    const int t    = threadIdx.x;
    const int w    = t >> 6;
    const int lane = t & 63;
    const int ln   = lane & 31;
    const int half = lane >> 5;
    const int h    = blockIdx.y;
    const int kvh  = h >> 2;
    const int q0   = blockIdx.x * BQ;
    const int wq0  = q0 + w * 32;
    const int qrow = wq0 + ln;

    short8 qf[8];
    {
        const float* qr = q + ((size_t)qrow * NH + h) * HD;
        #pragma unroll
        for (int k0 = 0; k0 < 8; ++k0) {
            const float* p4 = qr + k0 * 16 + half * 8;
            const float4 a = *(const float4*)(p4);
            const float4 b = *(const float4*)(p4 + 4);
            union { short8 v; unsigned int u[4]; } uu;
            uu.u[0] = f2bf2(a.x, a.y);
            uu.u[1] = f2bf2(a.z, a.w);
            uu.u[2] = f2bf2(b.x, b.y);
            uu.u[3] = f2bf2(b.z, b.w);
            qf[k0] = uu.v;
        }
    }

    float16 o0, o1, o2, o3;
    #pragma unroll
    for (int i = 0; i < 16; ++i) { o0[i] = 0.f; o1[i] = 0.f; o2[i] = 0.f; o3[i] = 0.f; }
    float m_run = -1e30f, l_run = 0.f;
    const int ntiles = (q0 + BQ) / BK;
    const int wqmax  = wq0 + 31;

    for (int it = 0; it < ntiles; ++it) {
        const int j0 = it * BK;
        __syncthreads();
        {
            const int key = t >> 2;
            const int db  = (t & 3) * 4;
            const float* kr = k + ((size_t)(j0 + key) * NKVH + kvh) * HD;
            #pragma unroll
            for (int r2 = 0; r2 < 8; ++r2) {
                const int d = db + r2 * 16;
                const float4 a = *(const float4*)(kr + d);
                *(unsigned int*)&ks[key * KSS + d]     = f2bf2(a.x, a.y);
                *(unsigned int*)&ks[key * KSS + d + 2] = f2bf2(a.z, a.w);
            }
        }
        {
            const int kp = (t & 31) * 2;
            const int db = (t >> 5) * 4;
            const float* vr0 = v + ((size_t)(j0 + kp) * NKVH + kvh) * HD;
            const float* vr1 = vr0 + NKVH * HD;
            #pragma unroll
            for (int r2 = 0; r2 < 4; ++r2) {
                const int d = db + r2 * 32;
                const float4 a = *(const float4*)(vr0 + d);
                const float4 b = *(const float4*)(vr1 + d);
                *(unsigned int*)&vt[(d + 0) * VTS + kp] = f2bf2(a.x, b.x);
                *(unsigned int*)&vt[(d + 1) * VTS + kp] = f2bf2(a.y, b.y);
                *(unsigned int*)&vt[(d + 2) * VTS + kp] = f2bf2(a.z, b.z);
                *(unsigned int*)&vt[(d + 3) * VTS + kp] = f2bf2(a.w, b.w);
            }
        }
        __syncthreads();
        if (j0 > wqmax) continue;

        float16 st0, st1;
        #pragma unroll
        for (int i = 0; i < 16; ++i) { st0[i] = 0.f; st1[i] = 0.f; }
        #pragma unroll
        for (int k0 = 0; k0 < 8; ++k0) {
            const short8 a0 = *(const short8*)&ks[ln * KSS + k0 * 16 + half * 8];
            const short8 a1 = *(const short8*)&ks[(32 + ln) * KSS + k0 * 16 + half * 8];
            st0 = __builtin_amdgcn_mfma_f32_32x32x16_bf16(a0, qf[k0], st0, 0, 0, 0);
            st1 = __builtin_amdgcn_mfma_f32_32x32x16_bf16(a1, qf[k0], st1, 0, 0, 0);
        }
        const bool need_mask = (j0 + BK - 1) > wq0;
        float mt = -1e30f;
        #pragma unroll
        for (int r = 0; r < 16; ++r) {
            const int kl = (r & 3) + 8 * (r >> 2) + 4 * half;
            float a0 = st0[r] * SCALE;
            float a1 = st1[r] * SCALE;
            if (need_mask) {
                if (j0 + kl > qrow)      a0 = -1e30f;
                if (j0 + 32 + kl > qrow) a1 = -1e30f;
            }
            st0[r] = a0; st1[r] = a1;
            mt = fmaxf(mt, fmaxf(a0, a1));
        }
        mt = fmaxf(mt, __shfl_xor(mt, 32, 64));
        const float mn = fmaxf(m_run, mt);
        float sm = 0.f;
        #pragma unroll
        for (int r = 0; r < 16; ++r) {
            const float e0 = __expf(st0[r] - mn);
            const float e1 = __expf(st1[r] - mn);
            st0[r] = e0; st1[r] = e1;
            sm += e0 + e1;
        }
        sm += __shfl_xor(sm, 32, 64);
        const float alpha = __expf(m_run - mn);
        m_run = mn;
        l_run = l_run * alpha + sm;

        unsigned short* psw = ps[w];
        #pragma unroll
        for (int r = 0; r < 16; r += 2) {
            const int kl = (r & 3) + 8 * (r >> 2) + 4 * half;
            *(unsigned int*)&psw[ln * PSS + kl]      = f2bf2(st0[r], st0[r + 1]);
            *(unsigned int*)&psw[ln * PSS + 32 + kl] = f2bf2(st1[r], st1[r + 1]);
        }
        if (half == 0) alf[w][ln] = alpha;
        #pragma unroll
        for (int r = 0; r < 16; ++r) {
            const int rl = (r & 3) + 8 * (r >> 2) + 4 * half;
            const float ar = alf[w][rl];
            o0[r] *= ar; o1[r] *= ar; o2[r] *= ar; o3[r] *= ar;
        }
        short8 af[4];
        #pragma unroll
        for (int kc = 0; kc < 4; ++kc)
            af[kc] = *(const short8*)&psw[ln * PSS + kc * 16 + half * 8];
        #pragma unroll
        for (int kc = 0; kc < 4; ++kc) {
            const short8 bv0 = *(const short8*)&vt[(ln)      * VTS + kc * 16 + half * 8];
            const short8 bv1 = *(const short8*)&vt[(32 + ln) * VTS + kc * 16 + half * 8];
            const short8 bv2 = *(const short8*)&vt[(64 + ln) * VTS + kc * 16 + half * 8];
            const short8 bv3 = *(const short8*)&vt[(96 + ln) * VTS + kc * 16 + half * 8];
            o0 = __builtin_amdgcn_mfma_f32_32x32x16_bf16(af[kc], bv0, o0, 0, 0, 0);
            o1 = __builtin_amdgcn_mfma_f32_32x32x16_bf16(af[kc], bv1, o1, 0, 0, 0);
            o2 = __builtin_amdgcn_mfma_f32_32x32x16_bf16(af[kc], bv2, o2, 0, 0, 0);
            o3 = __builtin_amdgcn_mfma_f32_32x32x16_bf16(af[kc], bv3, o3, 0, 0, 0);
        }
    }

    if (half == 0) alf[w][ln] = l_run;
    __builtin_amdgcn_s_waitcnt(0);
    #pragma unroll
    for (int r = 0; r < 16; ++r) {
        const int rl = (r & 3) + 8 * (r >> 2) + 4 * half;
        const float inv = 1.f / alf[w][rl];
        float* orow = out + ((size_t)(wq0 + rl) * NH + h) * HD;
        orow[ln]      = o0[r] * inv;
        orow[32 + ln] = o1[r] * inv;
        orow[64 + ln] = o2[r] * inv;
        orow[96 + ln] = o3[r] * inv;
    }
}

extern "C" void kernel_launch(void* const* d_in, const int* in_sizes, int n_in,
                              void* d_out, int out_size, void* d_ws, size_t ws_size,
                              hipStream_t stream) {
    const float* q = (const float*)d_in[0];
    const float* k = (const float*)d_in[1];
    const float* v = (const float*)d_in[2];
    float* out = (float*)d_out;
    if (ws_size >= (size_t)WS_NEED) {
        unsigned short* kb  = (unsigned short*)d_ws;
        unsigned short* vtw = kb + KB_ELEMS;
        cvt_k<<<KB_ELEMS / (256 * 4), 256, 0, stream>>>(k, kb);
        cvt_v<<<NKVH * 32, 256, 0, stream>>>(v, vtw);
        attn_fwd2<<<512, 256, 0, stream>>>(q, kb, vtw, out);
    } else {
        attn_fwd_fb<<<dim3(SEQ / BQ, NH), 256, 0, stream>>>(q, k, v, out);
    }
}